// Round 1
// baseline (27.138 us; speedup 1.0000x reference)
//
#include <hip/hip_runtime.h>
#include <hip/hip_bf16.h>

// Problem constants (from reference setup_inputs)
#define B_   32
#define N_   128
#define H_   8
#define D_   5      // MULTI_HOP_MAX_DIST (Dfull=8 clipped to 5)
#define F_   3
#define NSP_ 20     // NUM_SPATIAL
#define NE_  65     // edge_w rows (NUM_EDGE + 1)
#define NPTS (B_ * N_ * N_)          // 524288
#define MROWS (D_ * NE_)             // 325
#define MSTRIDE 12                   // padded row stride in floats (48B, 16B-aligned)
#define OUT_N 129
#define OUT_PLANE (OUT_N * OUT_N)    // 16641

// ---------------------------------------------------------------------------
// Kernel 1: precompute M[d][idx][h] = (1/3) * sum_k edge_w[idx][k] * edge_dis_w[d][k][h]
// into workspace (MROWS * H_ floats, row stride 8).
// ---------------------------------------------------------------------------
__global__ void prep_kernel(const float* __restrict__ edge_w,
                            const float* __restrict__ edge_dis_w,
                            float* __restrict__ M) {
    int t = blockIdx.x * blockDim.x + threadIdx.x;
    if (t >= MROWS * H_) return;
    int h = t & 7;
    int r = t >> 3;            // 0..324
    int d = r / NE_;           // 0..4
    int idx = r - d * NE_;     // 0..64
    float acc = 0.0f;
#pragma unroll
    for (int k = 0; k < H_; ++k)
        acc += edge_w[idx * H_ + k] * edge_dis_w[(d * H_ + k) * H_ + h];
    M[t] = acc * (1.0f / 3.0f);
}

// ---------------------------------------------------------------------------
// Kernel 2: borders.  out[b,h,0,0]=0; out[b,h,0,q]=t[h]; out[b,h,q,0]=t[h] (q>=1)
// One thread per (b,h,q), q in [0,129): writes both the row-0 and col-0 element.
// ---------------------------------------------------------------------------
__global__ void border_kernel(const float* __restrict__ graph_token,
                              float* __restrict__ out) {
    int t = blockIdx.x * blockDim.x + threadIdx.x;
    if (t >= B_ * H_ * OUT_N) return;
    int q = t % OUT_N;
    int bh = t / OUT_N;                 // b*8 + h
    float v = (q == 0) ? 0.0f : graph_token[bh & 7];
    size_t base = (size_t)bh * OUT_PLANE;
    out[base + q] = v;                  // row 0, col q
    out[base + (size_t)q * OUT_N] = v;  // row q, col 0
}

// ---------------------------------------------------------------------------
// Kernel 3: main.  One thread per (b,i,j) interior point; writes 8 outputs (h).
// ---------------------------------------------------------------------------
__global__ __launch_bounds__(256) void main_kernel(
        const int*   __restrict__ spatial_pos,
        const int*   __restrict__ edge_input,
        const float* __restrict__ spatial_w,
        const float* __restrict__ M,      // ws, MROWS*8 floats
        float*       __restrict__ out) {
    __shared__ float sM[MROWS * MSTRIDE];   // 325*12*4 = 15.6 KB (padded stride)
    __shared__ float sSW[NSP_ * H_];        // 160 floats

    // stage tables into LDS
    for (int t = threadIdx.x; t < MROWS * H_; t += 256) {
        int r = t >> 3, h = t & 7;
        sM[r * MSTRIDE + h] = M[t];
    }
    for (int t = threadIdx.x; t < NSP_ * H_; t += 256)
        sSW[t] = spatial_w[t];
    __syncthreads();

    int p = blockIdx.x * 256 + threadIdx.x;   // < NPTS
    int b  = p >> 14;                         // /(128*128)
    int ij = p & 16383;
    int i  = ij >> 7, j = ij & 127;

    int spos = spatial_pos[p];
    // sp: 0->1, 1->1, s>=2 -> s-1, then clip to <=5
    int s = (spos <= 1) ? 1 : (spos - 1);
    s = (s > D_) ? D_ : s;
    float inv = 1.0f / ((float)s + 1e-9f);

    // 24 ints per point; need first 15.  p*24 ints = p*96 B -> 16B aligned.
    const int4* e4 = reinterpret_cast<const int4*>(edge_input + (size_t)p * 24);
    int4 w0 = e4[0];
    int4 w1 = e4[1];
    int4 w2 = e4[2];
    int4 w3 = e4[3];
    int idx[15] = { w0.x, w0.y, w0.z, w0.w,
                    w1.x, w1.y, w1.z, w1.w,
                    w2.x, w2.y, w2.z, w2.w,
                    w3.x, w3.y, w3.z };

    float acc[H_];
#pragma unroll
    for (int h = 0; h < H_; ++h) acc[h] = 0.0f;

#pragma unroll
    for (int t = 0; t < D_ * F_; ++t) {
        int d = t / F_;                      // compile-time under full unroll
        int id = idx[t];
        id = (id < 0) ? 0 : ((id > NE_ - 1) ? NE_ - 1 : id);  // clip(ein,0,None) + safety
        const float4* row = reinterpret_cast<const float4*>(&sM[(d * NE_ + id) * MSTRIDE]);
        float4 lo = row[0];
        float4 hi = row[1];
        acc[0] += lo.x; acc[1] += lo.y; acc[2] += lo.z; acc[3] += lo.w;
        acc[4] += hi.x; acc[5] += hi.y; acc[6] += hi.z; acc[7] += hi.w;
    }

    const float* swr = &sSW[spos * H_];
    size_t obase = (size_t)b * (H_ * OUT_PLANE) + (size_t)(i + 1) * OUT_N + (j + 1);
#pragma unroll
    for (int h = 0; h < H_; ++h)
        out[obase + (size_t)h * OUT_PLANE] = swr[h] + acc[h] * inv;
}

extern "C" void kernel_launch(void* const* d_in, const int* in_sizes, int n_in,
                              void* d_out, int out_size, void* d_ws, size_t ws_size,
                              hipStream_t stream) {
    const int*   spatial_pos = (const int*)  d_in[0];
    const int*   edge_input  = (const int*)  d_in[1];
    const float* spatial_w   = (const float*)d_in[2];
    const float* edge_w      = (const float*)d_in[3];
    const float* edge_dis_w  = (const float*)d_in[4];
    const float* graph_token = (const float*)d_in[5];
    float* out = (float*)d_out;
    float* M   = (float*)d_ws;   // MROWS*8 floats = 10.4 KB

    // 1) precompute mixed table M
    prep_kernel<<<(MROWS * H_ + 255) / 256, 256, 0, stream>>>(edge_w, edge_dis_w, M);
    // 2) borders
    border_kernel<<<(B_ * H_ * OUT_N + 255) / 256, 256, 0, stream>>>(graph_token, out);
    // 3) interior
    main_kernel<<<NPTS / 256, 256, 0, stream>>>(spatial_pos, edge_input, spatial_w, M, out);
}